// Round 9
// baseline (461.540 us; speedup 1.0000x reference)
//
#include <hip/hip_runtime.h>
#include <hip/hip_bf16.h>
#include <math.h>

// N=768, D=32, C=10, H=256. Pairs = 768^2. MLP 149->256->256->1.
// feat@W1+b1 = |zi-zj|@W1[64:96] + (zi*zj)@W1[96:128] + R[i] + C[j]
//   R[i] = z[i]@W1[0:32] + p[i]@W1[128:138]
//   C[j] = z[j]@W1[32:64] + p[j]@W1[138:148] + b1 + hom*W1[148]
// Layer-1 K = 128: [0:64) feat(abs|prod), [64:72) R one-hot, [72:88) C one-hot,
// [88:96) R residual, [96:112) C residual, [112:128) zero-pad.
// Block = 128 pairs (8 i x 16 j), 512 thr, 8 waves (2m x 4n).
// L1 weights panel (64 KB) staged ONCE; W2 fragments read DIRECT from L2;
// h1 double-buffered in LDS; ONE barrier per 64-col chunk.

typedef _Float16 f16x8 __attribute__((ext_vector_type(8)));
typedef _Float16 f16x4 __attribute__((ext_vector_type(4)));
typedef float f32x4 __attribute__((ext_vector_type(4)));

#define MFMA16(a, b, c) __builtin_amdgcn_mfma_f32_16x16x32_f16(a, b, c, 0, 0, 0)

#define NN 768
#define HH 256

// ---------------- merged prep ----------------
// blocks [0,48): R/C transposed panels. Tile 64 i x 64 n -> RhT/ChT/R2hT/C2hT [256][768] f16.
// blocks [48,368): Wm[n][kk] f16 (kk<32: W1[64+kk][n]; else W1[96+kk-32][n]); W2t[n][k]=W2[k][n] f16.
__global__ void prep_all(const float* __restrict__ z, const float* __restrict__ lp,
                         const float* __restrict__ hom, const float* __restrict__ W1,
                         const float* __restrict__ b1, const float* __restrict__ W2,
                         _Float16* __restrict__ RhT, _Float16* __restrict__ ChT,
                         _Float16* __restrict__ R2hT, _Float16* __restrict__ C2hT,
                         _Float16* __restrict__ Wm, _Float16* __restrict__ W2t) {
  __shared__ float rt[64][65];
  __shared__ float ct[64][65];
  const int t = threadIdx.x;
  if (blockIdx.x < 48) {
    const int ib = (blockIdx.x % 12) * 64, nb = (blockIdx.x / 12) * 64;
    {
      const int il = t >> 2;          // 0..63
      const int ns = (t & 3) * 16;    // 0/16/32/48
      const int ig = ib + il;
      float racc[16], cacc[16];
      #pragma unroll
      for (int u = 0; u < 16; ++u) { racc[u] = 0.f; cacc[u] = 0.f; }
      for (int d = 0; d < 32; ++d) {
        float zr = z[ig * 32 + d];
        const float* wr = W1 + d * HH + nb + ns;
        const float* wc = W1 + (32 + d) * HH + nb + ns;
        #pragma unroll
        for (int u = 0; u < 16; ++u) { racc[u] += zr * wr[u]; cacc[u] += zr * wc[u]; }
      }
      #pragma unroll
      for (int k = 0; k < 10; ++k) {
        float pv = lp[ig * 10 + k];
        const float* wr = W1 + (128 + k) * HH + nb + ns;
        const float* wc = W1 + (138 + k) * HH + nb + ns;
        #pragma unroll
        for (int u = 0; u < 16; ++u) { racc[u] += pv * wr[u]; cacc[u] += pv * wc[u]; }
      }
      float hv = hom[0];
      #pragma unroll
      for (int u = 0; u < 16; ++u)
        cacc[u] += b1[nb + ns + u] + hv * W1[148 * HH + nb + ns + u];
      #pragma unroll
      for (int u = 0; u < 16; ++u) { rt[il][ns + u] = racc[u]; ct[il][ns + u] = cacc[u]; }
    }
    __syncthreads();
    {
      const int nl = t >> 2;          // 0..63
      const int is = (t & 3) * 16;    // 0/16/32/48
      _Float16 o1[16], o2[16], o3[16], o4[16];
      #pragma unroll
      for (int u = 0; u < 16; ++u) {
        float r = rt[is + u][nl];
        _Float16 rh = (_Float16)r;
        o1[u] = rh; o2[u] = (_Float16)(r - (float)rh);
        float c = ct[is + u][nl];
        _Float16 chv = (_Float16)c;
        o3[u] = chv; o4[u] = (_Float16)(c - (float)chv);
      }
      const long base = (long)(nb + nl) * NN + ib + is;
      *(int4*)&RhT[base]  = *(int4*)&o1[0];  *(int4*)&RhT[base + 8]  = *(int4*)&o1[8];
      *(int4*)&R2hT[base] = *(int4*)&o2[0];  *(int4*)&R2hT[base + 8] = *(int4*)&o2[8];
      *(int4*)&ChT[base]  = *(int4*)&o3[0];  *(int4*)&ChT[base + 8]  = *(int4*)&o3[8];
      *(int4*)&C2hT[base] = *(int4*)&o4[0];  *(int4*)&C2hT[base + 8] = *(int4*)&o4[8];
    }
  } else {
    int idx = (blockIdx.x - 48) * 256 + t;
    if (idx < 256 * 64) {
      int n = idx >> 6, kk = idx & 63;
      float v = (kk < 32) ? W1[(64 + kk) * HH + n] : W1[(96 + (kk - 32)) * HH + n];
      Wm[n * 64 + kk] = (_Float16)v;
    } else {
      int q = idx - 256 * 64;
      int n = q >> 8, k = q & 255;
      W2t[n * 256 + k] = (_Float16)W2[k * 256 + n];
    }
  }
}

// ---------------- fused MLP ----------------
// LDS: l1b [256 n][256B k] 64KB (staged once) | h1c [2][128 p][128B] 32KB | red 2KB.
// Swizzle: byte_off ^= (row&7)<<4 on 128B/256B rows.
__global__ __launch_bounds__(512, 2) void fused_mlp(
    const float* __restrict__ z,
    const _Float16* __restrict__ RhT, const _Float16* __restrict__ ChT,
    const _Float16* __restrict__ R2hT, const _Float16* __restrict__ C2hT,
    const _Float16* __restrict__ Wm, const _Float16* __restrict__ W2t,
    const float* __restrict__ b2, const float* __restrict__ W3,
    const float* __restrict__ b3, float* __restrict__ out) {
  __shared__ __align__(16) unsigned char lds[100352];
  unsigned char* l1b = lds;            // [256 n][256B]
  unsigned char* h1c = lds + 65536;    // [2][128 pair][128B]
  float* red = (float*)(lds + 98304);  // [128][4]

  const int tid = threadIdx.x;
  const int wid = tid >> 6;
  const int l = tid & 63;
  const int lr = l & 15;
  const int lg = l >> 4;
  const int wm = wid >> 2;      // 0..1  (m band: 64 pairs)
  const int wn = wid & 3;       // 0..3  (n slice: 64 cols)
  const int bi = blockIdx.x;    // 0..95  (8 i's)
  const int bj = blockIdx.y;    // 0..47  (16 j's)

  // ---- stage l1b ONCE: row n (0..255) = hidden col, 16 chunks of 16B over K=128 ----
  #pragma unroll
  for (int s = 0; s < 8; ++s) {
    int q = tid + 512 * s;
    int nl = q >> 4, ch = q & 15;
    int4 v;
    if (ch < 8)        v = *(const int4*)(Wm + nl * 64 + ch * 8);
    else if (ch == 8)  v = *(const int4*)(RhT + (long)nl * NN + bi * 8);
    else if (ch == 9)  v = *(const int4*)(ChT + (long)nl * NN + bj * 16);
    else if (ch == 10) v = *(const int4*)(ChT + (long)nl * NN + bj * 16 + 8);
    else if (ch == 11) v = *(const int4*)(R2hT + (long)nl * NN + bi * 8);
    else if (ch == 12) v = *(const int4*)(C2hT + (long)nl * NN + bj * 16);
    else if (ch == 13) v = *(const int4*)(C2hT + (long)nl * NN + bj * 16 + 8);
    else               v = (int4){0, 0, 0, 0};
    *(int4*)(l1b + nl * 256 + ((ch * 16) ^ ((nl & 7) << 4))) = v;
  }

  // ---- layer-1 feature fragments (B-operand; lane holds B[k=lg*8+t][pair=lr]) ----
  f16x8 a0[4], a1[4], a2[4], a3;
  {
    const float4* zj4 = (const float4*)(z + (bj * 16 + lr) * 32 + lg * 8);
    float4 zja = zj4[0], zjb = zj4[1];
    float zj[8] = {zja.x, zja.y, zja.z, zja.w, zjb.x, zjb.y, zjb.z, zjb.w};
    #pragma unroll
    for (int mt = 0; mt < 4; ++mt) {
      const int il = wm * 4 + mt;
      const float4* zi4 = (const float4*)(z + (bi * 8 + il) * 32 + lg * 8);
      float4 zia = zi4[0], zib = zi4[1];
      float zi[8] = {zia.x, zia.y, zia.z, zia.w, zib.x, zib.y, zib.z, zib.w};
      #pragma unroll
      for (int t = 0; t < 8; ++t) {
        float x = zi[t], y = zj[t];
        a0[mt][t] = (_Float16)fabsf(x - y);
        a1[mt][t] = (_Float16)(x * y);
      }
      #pragma unroll
      for (int t = 0; t < 8; ++t) {
        int k = 64 + lg * 8 + t;
        float v = (k < 72) ? (float)(k - 64 == il)
                : (k < 88) ? (float)(k - 72 == lr)
                           : (float)(k - 88 == il);
        a2[mt][t] = (_Float16)v;
      }
    }
    #pragma unroll
    for (int t = 0; t < 8; ++t) {
      int k = 96 + lg * 8 + t;
      a3[t] = (_Float16)(float)(k < 112 && (k - 96) == lr);
    }
  }

  const int hl = wn * 16 + lr;    // wave's hidden col within 64-chunk (L1 A row)

  // L1 chunk c -> h1c[buf]: D[hidden 16][pair 64], relu, f16 b64 pack.
  #define L1CHUNK(c, buf)                                                           \
    {                                                                               \
      f32x4 acc1[4];                                                                \
      _Pragma("unroll") for (int mt = 0; mt < 4; ++mt)                              \
        acc1[mt] = (f32x4){0.f, 0.f, 0.f, 0.f};                                     \
      _Pragma("unroll") for (int ks = 0; ks < 4; ++ks) {                            \
        int rowg = (c) * 64 + hl;                                                   \
        f16x8 wf = *(const f16x8*)(l1b + rowg * 256 +                               \
                                   ((ks * 64 + lg * 16) ^ ((hl & 7) << 4)));        \
        _Pragma("unroll") for (int mt = 0; mt < 4; ++mt) {                          \
          f16x8 ft = (ks == 0) ? a0[mt] : (ks == 1) ? a1[mt]                        \
                   : (ks == 2) ? a2[mt] : a3;                                       \
          acc1[mt] = MFMA16(wf, ft, acc1[mt]);                                      \
        }                                                                           \
      }                                                                             \
      _Pragma("unroll") for (int mt = 0; mt < 4; ++mt) {                            \
        f16x4 hv;                                                                   \
        _Pragma("unroll") for (int r = 0; r < 4; ++r) {                             \
          float v = acc1[mt][r];                                                    \
          hv[r] = (_Float16)(v > 0.f ? v : 0.f);                                    \
        }                                                                           \
        int pair = wm * 64 + mt * 16 + lr;                                          \
        *(f16x4*)(h1c + (buf) * 16384 + pair * 128 +                                \
                  ((wn * 32 + lg * 8) ^ ((lr & 7) << 4))) = hv;                     \
      }                                                                             \
    }

  // L2 chunk c from h1c[buf]; W2 fragments DIRECT from global (L2-resident).
  #define L2CHUNK(c, buf)                                                           \
    {                                                                               \
      _Pragma("unroll") for (int ks = 0; ks < 2; ++ks) {                            \
        f16x8 af[4];                                                                \
        _Pragma("unroll") for (int mt = 0; mt < 4; ++mt) {                          \
          int pair = wm * 64 + mt * 16 + lr;                                        \
          af[mt] = *(const f16x8*)(h1c + (buf) * 16384 + pair * 128 +               \
                                   ((ks * 64 + lg * 16) ^ ((lr & 7) << 4)));        \
        }                                                                           \
        _Pragma("unroll") for (int nt = 0; nt < 4; ++nt) {                          \
          int rw = wn * 64 + nt * 16 + lr;                                          \
          f16x8 bf = *(const f16x8*)(W2t + rw * 256 + (c) * 64 + ks * 32 + lg * 8); \
          _Pragma("unroll") for (int mt = 0; mt < 4; ++mt)                          \
            acc2[mt][nt] = MFMA16(af[mt], bf, acc2[mt][nt]);                        \
        }                                                                           \
      }                                                                             \
    }

  f32x4 acc2[4][4];
  #pragma unroll
  for (int mt = 0; mt < 4; ++mt)
    #pragma unroll
    for (int nt = 0; nt < 4; ++nt) acc2[mt][nt] = (f32x4){0.f, 0.f, 0.f, 0.f};

  __syncthreads();            // l1b staged
  L1CHUNK(0, 0);
  __syncthreads();            // h1c[0] ready
  L1CHUNK(1, 1); L2CHUNK(0, 0);
  __syncthreads();            // h1c[1] ready, h1c[0] consumed
  L1CHUNK(2, 0); L2CHUNK(1, 1);
  __syncthreads();
  L1CHUNK(3, 1); L2CHUNK(2, 0);
  __syncthreads();
  L2CHUNK(3, 1);

  // ---- epilogue: +b2, relu, dot W3 (fp32), cross-wave reduce, sigmoid ----
  float b2v[4], w3v[4];
  #pragma unroll
  for (int nt = 0; nt < 4; ++nt) {
    b2v[nt] = b2[wn * 64 + nt * 16 + lr];
    w3v[nt] = W3[wn * 64 + nt * 16 + lr];
  }
  const float b3v = b3[0];
  #pragma unroll
  for (int mt = 0; mt < 4; ++mt) {
    #pragma unroll
    for (int r = 0; r < 4; ++r) {
      float sum = 0.f;
      #pragma unroll
      for (int nt = 0; nt < 4; ++nt) {
        float h2 = acc2[mt][nt][r] + b2v[nt];
        h2 = h2 > 0.f ? h2 : 0.f;
        sum += h2 * w3v[nt];
      }
      sum += __shfl_xor(sum, 1);
      sum += __shfl_xor(sum, 2);
      sum += __shfl_xor(sum, 4);
      sum += __shfl_xor(sum, 8);
      if (lr == 0) {
        int row = wm * 64 + mt * 16 + 4 * lg + r;
        red[row * 4 + wn] = sum;
      }
    }
  }
  __syncthreads();
  if (tid < 128) {
    int row = tid;
    float logit = red[row * 4 + 0] + red[row * 4 + 1] + red[row * 4 + 2] + red[row * 4 + 3] + b3v;
    float prob = 1.f / (1.f + expf(-logit));
    out[(bi * 8 + (row >> 4)) * NN + bj * 16 + (row & 15)] = prob;
  }
}

// ---------------- symmetrize in-place: out = 0.5*(P + P^T), zero diag ----------------
__global__ void sym_kernel(float* __restrict__ out) {
  int idx = blockIdx.x * 256 + threadIdx.x;
  if (idx >= NN * NN) return;
  int i = idx / NN, j = idx % NN;
  if (i < j) {
    float a = out[i * NN + j], b = out[j * NN + i];
    float v = 0.5f * (a + b);
    out[i * NN + j] = v;
    out[j * NN + i] = v;
  } else if (i == j) {
    out[idx] = 0.f;
  }
}

extern "C" void kernel_launch(void* const* d_in, const int* in_sizes, int n_in,
                              void* d_out, int out_size, void* d_ws, size_t ws_size,
                              hipStream_t stream) {
  const float* z   = (const float*)d_in[0];
  const float* lp  = (const float*)d_in[1];
  const float* hom = (const float*)d_in[2];
  const float* W1  = (const float*)d_in[3];
  const float* b1  = (const float*)d_in[4];
  const float* W2  = (const float*)d_in[5];
  const float* b2  = (const float*)d_in[6];
  const float* W3  = (const float*)d_in[7];
  const float* b3  = (const float*)d_in[8];
  float* out = (float*)d_out;

  char* ws = (char*)d_ws;
  _Float16* RhT  = (_Float16*)(ws);                  // 256*768*2 = 393216 each
  _Float16* ChT  = (_Float16*)(ws + 393216);
  _Float16* R2hT = (_Float16*)(ws + 786432);
  _Float16* C2hT = (_Float16*)(ws + 1179648);
  _Float16* Wm   = (_Float16*)(ws + 1572864);        // 256*64*2 = 32768
  _Float16* W2t  = (_Float16*)(ws + 1605632);        // 256*256*2 = 131072 -> end 1736704

  prep_all<<<368, 256, 0, stream>>>(z, lp, hom, W1, b1, W2, RhT, ChT, R2hT, C2hT, Wm, W2t);
  fused_mlp<<<dim3(96, 48), 512, 0, stream>>>(z, RhT, ChT, R2hT, C2hT, Wm, W2t, b2, W3, b3, out);
  sym_kernel<<<2304, 256, 0, stream>>>(out);
}

// Round 12
// 415.850 us; speedup vs baseline: 1.1099x; 1.1099x over previous
//
#include <hip/hip_runtime.h>
#include <hip/hip_bf16.h>
#include <math.h>

// N=768, D=32, C=10, H=256. Pairs = 768^2. MLP 149->256->256->1.
// h1 = relu( |zi-zj|@W1[64:96] + (zi*zj)@W1[96:128]  (f16 MFMA, K=64)
//            + R[i] + C[j] )                          (exact f32 VALU add)
//   R[i] = z[i]@W1[0:32] + p[i]@W1[128:138]
//   C[j] = z[j]@W1[32:64] + p[j]@W1[138:148] + b1 + hom*W1[148]
// Block = 128 pairs (8 i x 16 j), 512 thr, 8 waves (2m x 4n), 4 chunks of 64 cols.
// NO weight LDS: Wm (32KB, all blocks identical -> L1-resident) and W2t read
// direct from cache. LDS = h1 double-buffer (2x16KB) + red only -> 34 KB
// -> 2 blocks/CU -> 4 waves/SIMD (fixes r9's latency-bound 2 waves/SIMD).

typedef _Float16 f16x8 __attribute__((ext_vector_type(8)));
typedef _Float16 f16x4 __attribute__((ext_vector_type(4)));
typedef float f32x4 __attribute__((ext_vector_type(4)));

#define MFMA16(a, b, c) __builtin_amdgcn_mfma_f32_16x16x32_f16(a, b, c, 0, 0, 0)

#define NN 768
#define HH 256

// ---------------- merged prep ----------------
// blocks [0,768): Rg[i][n], Cg[i][n] f32 (row-major, no transpose needed).
// blocks [768,1088): Wm[n][kk] f16 (kk<32: W1[64+kk][n]; else W1[96+kk-32][n]);
//                    W2t[n][k] = W2[k][n] f16.
__global__ void prep_all(const float* __restrict__ z, const float* __restrict__ lp,
                         const float* __restrict__ hom, const float* __restrict__ W1,
                         const float* __restrict__ b1, const float* __restrict__ W2,
                         float* __restrict__ Rg, float* __restrict__ Cg,
                         _Float16* __restrict__ Wm, _Float16* __restrict__ W2t) {
  const int t = threadIdx.x;
  if (blockIdx.x < 768) {
    const int i = blockIdx.x;
    const int n = t;
    float r = 0.f, c = 0.f;
    #pragma unroll 8
    for (int d = 0; d < 32; ++d) {
      float zv = z[i * 32 + d];
      r += zv * W1[d * HH + n];
      c += zv * W1[(32 + d) * HH + n];
    }
    #pragma unroll
    for (int k = 0; k < 10; ++k) {
      float pv = lp[i * 10 + k];
      r += pv * W1[(128 + k) * HH + n];
      c += pv * W1[(138 + k) * HH + n];
    }
    c += b1[n] + hom[0] * W1[148 * HH + n];
    Rg[i * HH + n] = r;
    Cg[i * HH + n] = c;
  } else {
    int idx = (blockIdx.x - 768) * 256 + t;
    if (idx < 256 * 64) {
      int n = idx >> 6, kk = idx & 63;
      float v = (kk < 32) ? W1[(64 + kk) * HH + n] : W1[(96 + (kk - 32)) * HH + n];
      Wm[n * 64 + kk] = (_Float16)v;
    } else {
      int q = idx - 256 * 64;
      int n = q >> 8, k = q & 255;
      W2t[n * 256 + k] = (_Float16)W2[k * 256 + n];
    }
  }
}

// ---------------- fused MLP ----------------
// LDS: h1c [2][128 pair][128B] 32KB | red [128][4] 2KB. Swizzle ^((lr&7)<<4).
__global__ __launch_bounds__(512, 4) void fused_mlp(
    const float* __restrict__ z,
    const float* __restrict__ Rg, const float* __restrict__ Cg,
    const _Float16* __restrict__ Wm, const _Float16* __restrict__ W2t,
    const float* __restrict__ b2, const float* __restrict__ W3,
    const float* __restrict__ b3, float* __restrict__ out) {
  __shared__ __align__(16) unsigned char lds[34816];
  unsigned char* h1c = lds;            // [2][128][128B]
  float* red = (float*)(lds + 32768);  // [128][4]

  const int tid = threadIdx.x;
  const int wid = tid >> 6;
  const int l = tid & 63;
  const int lr = l & 15;
  const int lg = l >> 4;
  const int wm = wid >> 2;      // 0..1  (m band: 64 pairs)
  const int wn = wid & 3;       // 0..3  (n slice: 64 cols)
  const int bi = blockIdx.x;    // 0..95  (8 i's)
  const int bj = blockIdx.y;    // 0..47  (16 j's)

  // ---- feature fragments a0 (|zi-zj|), a1 (zi*zj), built once; z regs freed ----
  f16x8 a0[4], a1[4];
  {
    const float4* zj4 = (const float4*)(z + (bj * 16 + lr) * 32 + lg * 8);
    float4 zja = zj4[0], zjb = zj4[1];
    float zj[8] = {zja.x, zja.y, zja.z, zja.w, zjb.x, zjb.y, zjb.z, zjb.w};
    #pragma unroll
    for (int mt = 0; mt < 4; ++mt) {
      const int il = wm * 4 + mt;
      const float4* zi4 = (const float4*)(z + (bi * 8 + il) * 32 + lg * 8);
      float4 zia = zi4[0], zib = zi4[1];
      float zi[8] = {zia.x, zia.y, zia.z, zia.w, zib.x, zib.y, zib.z, zib.w};
      #pragma unroll
      for (int t = 0; t < 8; ++t) {
        float x = zi[t], y = zj[t];
        a0[mt][t] = (_Float16)fabsf(x - y);
        a1[mt][t] = (_Float16)(x * y);
      }
    }
  }

  const int hl = wn * 16 + lr;    // wave's hidden col within 64-chunk (L1 A row)

  // L1 chunk c -> h1c[buf]: D[hidden 16][pair 64]; +R+C (f32), relu, f16 b64 pack.
  // Weight frags direct from Wm (L1-cache-resident, 32KB shared by all blocks).
  #define L1CHUNK(c, buf)                                                           \
    {                                                                               \
      const _Float16* wrow = Wm + ((c) * 64 + hl) * 64 + lg * 8;                    \
      f16x8 wf0 = *(const f16x8*)(wrow);                                            \
      f16x8 wf1 = *(const f16x8*)(wrow + 32);                                       \
      _Pragma("unroll") for (int mt = 0; mt < 4; ++mt) {                            \
        f32x4 acc1 = (f32x4){0.f, 0.f, 0.f, 0.f};                                   \
        acc1 = MFMA16(wf0, a0[mt], acc1);                                           \
        acc1 = MFMA16(wf1, a1[mt], acc1);                                           \
        const int il = wm * 4 + mt;                                                 \
        const int hoff = (c) * 64 + wn * 16 + 4 * lg;                               \
        f32x4 rr = *(const f32x4*)(Rg + (bi * 8 + il) * HH + hoff);                 \
        f32x4 cc = *(const f32x4*)(Cg + (bj * 16 + lr) * HH + hoff);                \
        f16x4 hv;                                                                   \
        _Pragma("unroll") for (int r = 0; r < 4; ++r) {                             \
          float v = acc1[r] + rr[r] + cc[r];                                        \
          hv[r] = (_Float16)(v > 0.f ? v : 0.f);                                    \
        }                                                                           \
        int pair = wm * 64 + mt * 16 + lr;                                          \
        *(f16x4*)(h1c + (buf) * 16384 + pair * 128 +                                \
                  ((wn * 32 + lg * 8) ^ ((lr & 7) << 4))) = hv;                     \
      }                                                                             \
    }

  // L2 chunk c from h1c[buf]; W2 fragments direct from cache.
  #define L2CHUNK(c, buf)                                                           \
    {                                                                               \
      _Pragma("unroll") for (int ks = 0; ks < 2; ++ks) {                            \
        f16x8 af[4];                                                                \
        _Pragma("unroll") for (int mt = 0; mt < 4; ++mt) {                          \
          int pair = wm * 64 + mt * 16 + lr;                                        \
          af[mt] = *(const f16x8*)(h1c + (buf) * 16384 + pair * 128 +               \
                                   ((ks * 64 + lg * 16) ^ ((lr & 7) << 4)));        \
        }                                                                           \
        _Pragma("unroll") for (int nt = 0; nt < 4; ++nt) {                          \
          int rw = wn * 64 + nt * 16 + lr;                                          \
          f16x8 bf = *(const f16x8*)(W2t + rw * 256 + (c) * 64 + ks * 32 + lg * 8); \
          _Pragma("unroll") for (int mt = 0; mt < 4; ++mt)                          \
            acc2[mt][nt] = MFMA16(af[mt], bf, acc2[mt][nt]);                        \
        }                                                                           \
      }                                                                             \
    }

  f32x4 acc2[4][4];
  #pragma unroll
  for (int mt = 0; mt < 4; ++mt)
    #pragma unroll
    for (int nt = 0; nt < 4; ++nt) acc2[mt][nt] = (f32x4){0.f, 0.f, 0.f, 0.f};

  L1CHUNK(0, 0);
  __syncthreads();            // h1c[0] ready
  L1CHUNK(1, 1); L2CHUNK(0, 0);
  __syncthreads();            // h1c[1] ready, h1c[0] consumed
  L1CHUNK(2, 0); L2CHUNK(1, 1);
  __syncthreads();
  L1CHUNK(3, 1); L2CHUNK(2, 0);
  __syncthreads();
  L2CHUNK(3, 1);

  // ---- epilogue: +b2, relu, dot W3 (fp32), cross-wave reduce, sigmoid ----
  float b2v[4], w3v[4];
  #pragma unroll
  for (int nt = 0; nt < 4; ++nt) {
    b2v[nt] = b2[wn * 64 + nt * 16 + lr];
    w3v[nt] = W3[wn * 64 + nt * 16 + lr];
  }
  const float b3v = b3[0];
  #pragma unroll
  for (int mt = 0; mt < 4; ++mt) {
    #pragma unroll
    for (int r = 0; r < 4; ++r) {
      float sum = 0.f;
      #pragma unroll
      for (int nt = 0; nt < 4; ++nt) {
        float h2 = acc2[mt][nt][r] + b2v[nt];
        h2 = h2 > 0.f ? h2 : 0.f;
        sum += h2 * w3v[nt];
      }
      sum += __shfl_xor(sum, 1);
      sum += __shfl_xor(sum, 2);
      sum += __shfl_xor(sum, 4);
      sum += __shfl_xor(sum, 8);
      if (lr == 0) {
        int row = wm * 64 + mt * 16 + 4 * lg + r;
        red[row * 4 + wn] = sum;
      }
    }
  }
  __syncthreads();
  if (tid < 128) {
    int row = tid;
    float logit = red[row * 4 + 0] + red[row * 4 + 1] + red[row * 4 + 2] + red[row * 4 + 3] + b3v;
    float prob = 1.f / (1.f + expf(-logit));
    out[(bi * 8 + (row >> 4)) * NN + bj * 16 + (row & 15)] = prob;
  }
}

// ---------------- symmetrize in-place: out = 0.5*(P + P^T), zero diag ----------------
__global__ void sym_kernel(float* __restrict__ out) {
  int idx = blockIdx.x * 256 + threadIdx.x;
  if (idx >= NN * NN) return;
  int i = idx / NN, j = idx % NN;
  if (i < j) {
    float a = out[i * NN + j], b = out[j * NN + i];
    float v = 0.5f * (a + b);
    out[i * NN + j] = v;
    out[j * NN + i] = v;
  } else if (i == j) {
    out[idx] = 0.f;
  }
}

extern "C" void kernel_launch(void* const* d_in, const int* in_sizes, int n_in,
                              void* d_out, int out_size, void* d_ws, size_t ws_size,
                              hipStream_t stream) {
  const float* z   = (const float*)d_in[0];
  const float* lp  = (const float*)d_in[1];
  const float* hom = (const float*)d_in[2];
  const float* W1  = (const float*)d_in[3];
  const float* b1  = (const float*)d_in[4];
  const float* W2  = (const float*)d_in[5];
  const float* b2  = (const float*)d_in[6];
  const float* W3  = (const float*)d_in[7];
  const float* b3  = (const float*)d_in[8];
  float* out = (float*)d_out;

  char* ws = (char*)d_ws;
  float*    Rg  = (float*)(ws);                      // 768*256*4 = 786432
  float*    Cg  = (float*)(ws + 786432);             // 786432
  _Float16* Wm  = (_Float16*)(ws + 1572864);         // 256*64*2 = 32768
  _Float16* W2t = (_Float16*)(ws + 1605632);         // 256*256*2 = 131072 -> end 1736704

  prep_all<<<1088, 256, 0, stream>>>(z, lp, hom, W1, b1, W2, Rg, Cg, Wm, W2t);
  fused_mlp<<<dim3(96, 48), 512, 0, stream>>>(z, Rg, Cg, Wm, W2t, b2, W3, b3, out);
  sym_kernel<<<2304, 256, 0, stream>>>(out);
}

// Round 13
// 362.005 us; speedup vs baseline: 1.2750x; 1.1487x over previous
//
#include <hip/hip_runtime.h>
#include <hip/hip_bf16.h>
#include <math.h>

// N=768, D=32, C=10, H=256. Pairs = 768^2. MLP 149->256->256->1.
// h1 = relu( |zi-zj|@W1[64:96] + (zi*zj)@W1[96:128]  (f16 MFMA, K=64)
//            + R[i] + C[j] )                          (exact f32 VALU add)
//   R[i] = z[i]@W1[0:32] + p[i]@W1[128:138]
//   C[j] = z[j]@W1[32:64] + p[j]@W1[138:148] + b1 + hom*W1[148]
// Block = 128 pairs (8 i x 16 j), 512 thr, 8 waves (2m x 4n), 4 chunks of 64 cols.
// NO weight LDS: Wm (32KB, identical for all blocks -> cache-resident) and W2t
// read direct from cache. LDS = h1 double-buffer (2x16KB) + red -> 34 KB.
// __launch_bounds__(512,2): EMPIRICALLY cap=128 VGPR (r4/r5/r9: 124/120/108).
// (512,4) gave cap=64 -> acc2 spilled -> 850 MB scratch traffic (r12).

typedef _Float16 f16x8 __attribute__((ext_vector_type(8)));
typedef _Float16 f16x4 __attribute__((ext_vector_type(4)));
typedef float f32x4 __attribute__((ext_vector_type(4)));

#define MFMA16(a, b, c) __builtin_amdgcn_mfma_f32_16x16x32_f16(a, b, c, 0, 0, 0)

#define NN 768
#define HH 256

// ---------------- merged prep ----------------
// blocks [0,768): Rg[i][n], Cg[i][n] f32 (row-major).
// blocks [768,1088): Wm[n][kk] f16 (kk<32: W1[64+kk][n]; else W1[96+kk-32][n]);
//                    W2t[n][k] = W2[k][n] f16.
__global__ void prep_all(const float* __restrict__ z, const float* __restrict__ lp,
                         const float* __restrict__ hom, const float* __restrict__ W1,
                         const float* __restrict__ b1, const float* __restrict__ W2,
                         float* __restrict__ Rg, float* __restrict__ Cg,
                         _Float16* __restrict__ Wm, _Float16* __restrict__ W2t) {
  const int t = threadIdx.x;
  if (blockIdx.x < 768) {
    const int i = blockIdx.x;
    const int n = t;
    float r = 0.f, c = 0.f;
    #pragma unroll 8
    for (int d = 0; d < 32; ++d) {
      float zv = z[i * 32 + d];
      r += zv * W1[d * HH + n];
      c += zv * W1[(32 + d) * HH + n];
    }
    #pragma unroll
    for (int k = 0; k < 10; ++k) {
      float pv = lp[i * 10 + k];
      r += pv * W1[(128 + k) * HH + n];
      c += pv * W1[(138 + k) * HH + n];
    }
    c += b1[n] + hom[0] * W1[148 * HH + n];
    Rg[i * HH + n] = r;
    Cg[i * HH + n] = c;
  } else {
    int idx = (blockIdx.x - 768) * 256 + t;
    if (idx < 256 * 64) {
      int n = idx >> 6, kk = idx & 63;
      float v = (kk < 32) ? W1[(64 + kk) * HH + n] : W1[(96 + (kk - 32)) * HH + n];
      Wm[n * 64 + kk] = (_Float16)v;
    } else {
      int q = idx - 256 * 64;
      int n = q >> 8, k = q & 255;
      W2t[n * 256 + k] = (_Float16)W2[k * 256 + n];
    }
  }
}

// ---------------- fused MLP ----------------
// LDS: h1c [2][128 pair][128B] 32KB | red [128][4] 2KB. Swizzle ^((lr&7)<<4).
__global__ __launch_bounds__(512, 2) void fused_mlp(
    const float* __restrict__ z,
    const float* __restrict__ Rg, const float* __restrict__ Cg,
    const _Float16* __restrict__ Wm, const _Float16* __restrict__ W2t,
    const float* __restrict__ b2, const float* __restrict__ W3,
    const float* __restrict__ b3, float* __restrict__ out) {
  __shared__ __align__(16) unsigned char lds[34816];
  unsigned char* h1c = lds;            // [2][128][128B]
  float* red = (float*)(lds + 32768);  // [128][4]

  const int tid = threadIdx.x;
  const int wid = tid >> 6;
  const int l = tid & 63;
  const int lr = l & 15;
  const int lg = l >> 4;
  const int wm = wid >> 2;      // 0..1  (m band: 64 pairs)
  const int wn = wid & 3;       // 0..3  (n slice: 64 cols)
  const int bi = blockIdx.x;    // 0..95  (8 i's)
  const int bj = blockIdx.y;    // 0..47  (16 j's)

  // ---- feature fragments a0 (|zi-zj|), a1 (zi*zj), built once; z regs freed ----
  f16x8 a0[4], a1[4];
  {
    const float4* zj4 = (const float4*)(z + (bj * 16 + lr) * 32 + lg * 8);
    float4 zja = zj4[0], zjb = zj4[1];
    float zj[8] = {zja.x, zja.y, zja.z, zja.w, zjb.x, zjb.y, zjb.z, zjb.w};
    #pragma unroll
    for (int mt = 0; mt < 4; ++mt) {
      const int il = wm * 4 + mt;
      const float4* zi4 = (const float4*)(z + (bi * 8 + il) * 32 + lg * 8);
      float4 zia = zi4[0], zib = zi4[1];
      float zi[8] = {zia.x, zia.y, zia.z, zia.w, zib.x, zib.y, zib.z, zib.w};
      #pragma unroll
      for (int t = 0; t < 8; ++t) {
        float x = zi[t], y = zj[t];
        a0[mt][t] = (_Float16)fabsf(x - y);
        a1[mt][t] = (_Float16)(x * y);
      }
    }
  }

  const int hl = wn * 16 + lr;    // wave's hidden col within 64-chunk (L1 A row)

  // L1 chunk c -> h1c[buf]: D[hidden 16][pair 64]; +R+C (f32), relu, f16 b64 pack.
  // Weight frags direct from Wm (cache-resident, 32KB shared by all blocks).
  #define L1CHUNK(c, buf)                                                           \
    {                                                                               \
      const _Float16* wrow = Wm + ((c) * 64 + hl) * 64 + lg * 8;                    \
      f16x8 wf0 = *(const f16x8*)(wrow);                                            \
      f16x8 wf1 = *(const f16x8*)(wrow + 32);                                       \
      _Pragma("unroll") for (int mt = 0; mt < 4; ++mt) {                            \
        f32x4 acc1 = (f32x4){0.f, 0.f, 0.f, 0.f};                                   \
        acc1 = MFMA16(wf0, a0[mt], acc1);                                           \
        acc1 = MFMA16(wf1, a1[mt], acc1);                                           \
        const int il = wm * 4 + mt;                                                 \
        const int hoff = (c) * 64 + wn * 16 + 4 * lg;                               \
        f32x4 rr = *(const f32x4*)(Rg + (bi * 8 + il) * HH + hoff);                 \
        f32x4 cc = *(const f32x4*)(Cg + (bj * 16 + lr) * HH + hoff);                \
        f16x4 hv;                                                                   \
        _Pragma("unroll") for (int r = 0; r < 4; ++r) {                             \
          float v = acc1[r] + rr[r] + cc[r];                                        \
          hv[r] = (_Float16)(v > 0.f ? v : 0.f);                                    \
        }                                                                           \
        int pair = wm * 64 + mt * 16 + lr;                                          \
        *(f16x4*)(h1c + (buf) * 16384 + pair * 128 +                                \
                  ((wn * 32 + lg * 8) ^ ((lr & 7) << 4))) = hv;                     \
      }                                                                             \
    }

  // L2 chunk c from h1c[buf]; W2 fragments direct from cache.
  #define L2CHUNK(c, buf)                                                           \
    {                                                                               \
      _Pragma("unroll") for (int ks = 0; ks < 2; ++ks) {                            \
        f16x8 af[4];                                                                \
        _Pragma("unroll") for (int mt = 0; mt < 4; ++mt) {                          \
          int pair = wm * 64 + mt * 16 + lr;                                        \
          af[mt] = *(const f16x8*)(h1c + (buf) * 16384 + pair * 128 +               \
                                   ((ks * 64 + lg * 16) ^ ((lr & 7) << 4)));        \
        }                                                                           \
        _Pragma("unroll") for (int nt = 0; nt < 4; ++nt) {                          \
          int rw = wn * 64 + nt * 16 + lr;                                          \
          f16x8 bf = *(const f16x8*)(W2t + rw * 256 + (c) * 64 + ks * 32 + lg * 8); \
          _Pragma("unroll") for (int mt = 0; mt < 4; ++mt)                          \
            acc2[mt][nt] = MFMA16(af[mt], bf, acc2[mt][nt]);                        \
        }                                                                           \
      }                                                                             \
    }

  f32x4 acc2[4][4];
  #pragma unroll
  for (int mt = 0; mt < 4; ++mt)
    #pragma unroll
    for (int nt = 0; nt < 4; ++nt) acc2[mt][nt] = (f32x4){0.f, 0.f, 0.f, 0.f};

  L1CHUNK(0, 0);
  __syncthreads();            // h1c[0] ready
  L1CHUNK(1, 1); L2CHUNK(0, 0);
  __syncthreads();            // h1c[1] ready, h1c[0] consumed
  L1CHUNK(2, 0); L2CHUNK(1, 1);
  __syncthreads();
  L1CHUNK(3, 1); L2CHUNK(2, 0);
  __syncthreads();
  L2CHUNK(3, 1);

  // ---- epilogue: +b2, relu, dot W3 (fp32), cross-wave reduce, sigmoid ----
  float b2v[4], w3v[4];
  #pragma unroll
  for (int nt = 0; nt < 4; ++nt) {
    b2v[nt] = b2[wn * 64 + nt * 16 + lr];
    w3v[nt] = W3[wn * 64 + nt * 16 + lr];
  }
  const float b3v = b3[0];
  #pragma unroll
  for (int mt = 0; mt < 4; ++mt) {
    #pragma unroll
    for (int r = 0; r < 4; ++r) {
      float sum = 0.f;
      #pragma unroll
      for (int nt = 0; nt < 4; ++nt) {
        float h2 = acc2[mt][nt][r] + b2v[nt];
        h2 = h2 > 0.f ? h2 : 0.f;
        sum += h2 * w3v[nt];
      }
      sum += __shfl_xor(sum, 1);
      sum += __shfl_xor(sum, 2);
      sum += __shfl_xor(sum, 4);
      sum += __shfl_xor(sum, 8);
      if (lr == 0) {
        int row = wm * 64 + mt * 16 + 4 * lg + r;
        red[row * 4 + wn] = sum;
      }
    }
  }
  __syncthreads();
  if (tid < 128) {
    int row = tid;
    float logit = red[row * 4 + 0] + red[row * 4 + 1] + red[row * 4 + 2] + red[row * 4 + 3] + b3v;
    float prob = 1.f / (1.f + expf(-logit));
    out[(bi * 8 + (row >> 4)) * NN + bj * 16 + (row & 15)] = prob;
  }
}

// ---------------- symmetrize in-place: out = 0.5*(P + P^T), zero diag ----------------
__global__ void sym_kernel(float* __restrict__ out) {
  int idx = blockIdx.x * 256 + threadIdx.x;
  if (idx >= NN * NN) return;
  int i = idx / NN, j = idx % NN;
  if (i < j) {
    float a = out[i * NN + j], b = out[j * NN + i];
    float v = 0.5f * (a + b);
    out[i * NN + j] = v;
    out[j * NN + i] = v;
  } else if (i == j) {
    out[idx] = 0.f;
  }
}

extern "C" void kernel_launch(void* const* d_in, const int* in_sizes, int n_in,
                              void* d_out, int out_size, void* d_ws, size_t ws_size,
                              hipStream_t stream) {
  const float* z   = (const float*)d_in[0];
  const float* lp  = (const float*)d_in[1];
  const float* hom = (const float*)d_in[2];
  const float* W1  = (const float*)d_in[3];
  const float* b1  = (const float*)d_in[4];
  const float* W2  = (const float*)d_in[5];
  const float* b2  = (const float*)d_in[6];
  const float* W3  = (const float*)d_in[7];
  const float* b3  = (const float*)d_in[8];
  float* out = (float*)d_out;

  char* ws = (char*)d_ws;
  float*    Rg  = (float*)(ws);                      // 768*256*4 = 786432
  float*    Cg  = (float*)(ws + 786432);             // 786432
  _Float16* Wm  = (_Float16*)(ws + 1572864);         // 256*64*2 = 32768
  _Float16* W2t = (_Float16*)(ws + 1605632);         // 256*256*2 = 131072 -> end 1736704

  prep_all<<<1088, 256, 0, stream>>>(z, lp, hom, W1, b1, W2, Rg, Cg, Wm, W2t);
  fused_mlp<<<dim3(96, 48), 512, 0, stream>>>(z, Rg, Cg, Wm, W2t, b2, W3, b3, out);
  sym_kernel<<<2304, 256, 0, stream>>>(out);
}